// Round 2
// baseline (8255.252 us; speedup 1.0000x reference)
//
#include <hip/hip_runtime.h>

#define B_ 256
#define T_ 256
#define E_ 512
#define U_ 1024
#define G_ 4096   // 4*U
#define V_ 50000
#define TC_ 32    // timesteps per x_proj chunk
#define NCH_ 8    // T_/TC_
#define RG_ 4     // row groups (scan)
#define CG_ 64    // col groups (scan)

typedef __bf16 bf16x8 __attribute__((ext_vector_type(8)));
typedef float f32x4 __attribute__((ext_vector_type(4)));
typedef unsigned short us8 __attribute__((ext_vector_type(8)));
typedef unsigned short us4 __attribute__((ext_vector_type(4)));

__device__ __forceinline__ unsigned short f2bf(float f) {
  union { float f; unsigned u; } v; v.f = f;
  unsigned u = v.u;
  u = (u + 0x7FFFu + ((u >> 16) & 1u)) >> 16;   // RNE
  return (unsigned short)u;
}
__device__ __forceinline__ float bf2f(unsigned short h) {
  union { unsigned u; float f; } v; v.u = ((unsigned)h) << 16;
  return v.f;
}
__device__ __forceinline__ float sigm_(float x) { return 1.f / (1.f + __expf(-x)); }
__device__ __forceinline__ float tanh_(float x) { return 2.f / (1.f + __expf(-2.f * x)) - 1.f; }

__device__ __forceinline__ void gload16(const void* g, void* l) {
  __builtin_amdgcn_global_load_lds((const __attribute__((address_space(1))) void*)g,
                                   (__attribute__((address_space(3))) void*)l, 16, 0, 0);
}

// packed column p -> original gate column: p = cg*64 + gg*16 + ul  ->  gg*1024 + cg*16 + ul
__device__ __forceinline__ int orig_col(int p) {
  return (((p >> 4) & 3) << 10) + ((p >> 6) << 4) + (p & 15);
}

// ---------------- prep: f32 -> bf16 (row-major) ----------------
__global__ void cvt_bf16_kernel(const float* __restrict__ in, unsigned short* __restrict__ out, long n) {
  long i = (((long)blockIdx.x * blockDim.x) + threadIdx.x) << 3;
  long stride = ((long)gridDim.x * blockDim.x) << 3;
  for (; i < n; i += stride) {
    float4 x = *(const float4*)(in + i);
    float4 y = *(const float4*)(in + i + 4);
    us8 v;
    v[0] = f2bf(x.x); v[1] = f2bf(x.y); v[2] = f2bf(x.z); v[3] = f2bf(x.w);
    v[4] = f2bf(y.x); v[5] = f2bf(y.y); v[6] = f2bf(y.z); v[7] = f2bf(y.w);
    *(us8*)(out + i) = v;
  }
}

// ---------------- prep: pack Wx [K][4096] f32 -> [K/8][4096 packed][8] bf16 ----------------
__global__ void pack_wx_kernel(const float* __restrict__ w, unsigned short* __restrict__ out, int total) {
  int t = blockIdx.x * blockDim.x + threadIdx.x;   // over (K/8)*4096
  if (t >= total) return;
  int kb = t >> 12, n = t & 4095;
  int oc = orig_col(n);
  us8 v;
#pragma unroll
  for (int ki = 0; ki < 8; ki++) v[ki] = f2bf(w[(size_t)(kb * 8 + ki) * G_ + oc]);
  *(us8*)(out + (size_t)t * 8) = v;
}

// ---------------- prep: pack Wh into scan B-fragment order ----------------
// flat idx = (((cg*2+wn)*2 + ns)*32 + k)*64 + lane ; 8 bf16 each:
//   element i: Wh[k*32 + (lane>>4)*8 + i][orig_col(cg*64 + wn*32 + ns*16 + (lane&15))]
__global__ void pack_wh2_kernel(const float* __restrict__ w, unsigned short* __restrict__ out) {
  int t = blockIdx.x * blockDim.x + threadIdx.x;   // 524288 total
  int ln = t & 63;
  int k = (t >> 6) & 31;
  int ns = (t >> 11) & 1;
  int cgwn = t >> 12;           // 0..127
  int cg = cgwn >> 1, wn = cgwn & 1;
  int q = wn * 32 + ns * 16 + (ln & 15);
  int oc = orig_col(cg * 64 + q);
  int kr = k * 32 + (ln >> 4) * 8;
  us8 v;
#pragma unroll
  for (int i = 0; i < 8; i++) v[i] = f2bf(w[(size_t)(kr + i) * G_ + oc]);
  *(us8*)(out + (size_t)t * 8) = v;
}

// ---------------- x_proj: gather(emb) @ Wx + b -> bf16 [TC*B][G packed] ----------------
#define XP_BM 128
#define XP_BN 128
#define XP_KC 64
__global__ __launch_bounds__(256, 2) void xproj_kernel(
    const int* __restrict__ sent, const unsigned short* __restrict__ embb,
    const unsigned short* __restrict__ wxp, const float* __restrict__ bias,
    unsigned short* __restrict__ xp, int t0)
{
  __shared__ __align__(16) unsigned short sA[2][XP_BM * XP_KC];
  __shared__ __align__(16) unsigned short sB[2][XP_KC * XP_BN];
  __shared__ int tok[XP_BM];

  const int tid = threadIdx.x;
  const int lane = tid & 63;
  const int wid = tid >> 6;
  const int m0 = blockIdx.x * XP_BM;   // row = tl*256 + b  (chunk-local)
  const int n0 = blockIdx.y * XP_BN;

  if (tid < XP_BM) {
    int row = m0 + tid;
    int tl = row >> 8, b = row & 255;
    tok[tid] = sent[b * T_ + t0 + tl];
  }
  __syncthreads();

  auto stageA = [&](int bf, int kc) {
#pragma unroll
    for (int ii = 0; ii < 4; ii++) {
      int i = wid * 4 + ii;
      int m = i * 8 + (lane >> 3);
      int cl = lane & 7;
      const unsigned short* src = embb + (size_t)tok[m] * E_ + kc + ((cl ^ (m & 7)) << 3);
      gload16(src, &sA[bf][i * 512]);
    }
  };
  auto stageB = [&](int bf, int kc) {
    int kb0 = kc >> 3;
#pragma unroll
    for (int jj = 0; jj < 4; jj++) {
      int j = wid * 4 + jj;
      int r = j >> 1;
      int nl = ((j & 1) << 6) + lane;
      int n = nl ^ r;
      const unsigned short* src = wxp + ((size_t)(kb0 + r) * G_ + n0 + n) * 8;
      gload16(src, &sB[bf][j * 512]);
    }
  };

  f32x4 acc[4][4];
#pragma unroll
  for (int i = 0; i < 4; i++)
#pragma unroll
    for (int j = 0; j < 4; j++) acc[i][j] = f32x4{0.f, 0.f, 0.f, 0.f};

  const int wm = wid >> 1, wn = wid & 1;

  stageA(0, 0); stageB(0, 0);
  for (int it = 0; it < E_ / XP_KC; it++) {   // 8
    int bf = it & 1;
    __syncthreads();
    if (it < E_ / XP_KC - 1) { stageA(bf ^ 1, (it + 1) * XP_KC); stageB(bf ^ 1, (it + 1) * XP_KC); }
#pragma unroll
    for (int kk = 0; kk < 2; kk++) {
      int c = (kk << 2) + (lane >> 4);
      bf16x8 a[4], b[4];
#pragma unroll
      for (int ms = 0; ms < 4; ms++) {
        int m = (wm << 6) + (ms << 4) + (lane & 15);
        a[ms] = *(const bf16x8*)&sA[bf][m * 64 + ((c ^ (m & 7)) << 3)];
      }
#pragma unroll
      for (int ns = 0; ns < 4; ns++) {
        int n = (wn << 6) + (ns << 4) + (lane & 15);
        b[ns] = *(const bf16x8*)&sB[bf][((c << 7) + (n ^ c)) << 3];
      }
#pragma unroll
      for (int ms = 0; ms < 4; ms++)
#pragma unroll
        for (int ns = 0; ns < 4; ns++)
          acc[ms][ns] = __builtin_amdgcn_mfma_f32_16x16x32_bf16(a[ms], b[ns], acc[ms][ns], 0, 0, 0);
    }
  }

#pragma unroll
  for (int ns = 0; ns < 4; ns++) {
    int col = n0 + (wn << 6) + (ns << 4) + (lane & 15);
    float bv = bias[orig_col(col)];
#pragma unroll
    for (int ms = 0; ms < 4; ms++) {
      int rbase = m0 + (wm << 6) + (ms << 4) + ((lane >> 4) << 2);
#pragma unroll
      for (int rr = 0; rr < 4; rr++)
        xp[(size_t)(rbase + rr) * G_ + col] = f2bf(acc[ms][ns][rr] + bv);
    }
  }
}

// ---------------- persistent scan: 32 timesteps, 256 blocks (4 RG x 64 CG) ----------------
__global__ __launch_bounds__(256, 1) void scan_kernel(
    const unsigned short* __restrict__ xpc,   // [TC][256][4096 packed] bf16 (bias incl.)
    const unsigned short* __restrict__ whp2,  // packed Wh B-fragments
    unsigned short* __restrict__ hbuf,        // [2][256][1024] bf16
    float* __restrict__ cst,                  // [256][1024] f32
    int* __restrict__ cnt,                    // [T+1][RG] arrival counters
    int t0)
{
  __shared__ __align__(16) char smem[64 * 1024 * 2];   // 128 KB
  unsigned short* sA = (unsigned short*)smem;           // [64 rows][1024 k] swizzled
  float (*sG)[64] = (float(*)[64])smem;                 // aliased gate-exchange [64][64]

  const int tid = threadIdx.x, lane = tid & 63, w = tid >> 6;
  const int wm = w >> 1, wn = w & 1;
  const int rg = (int)blockIdx.x >> 6, cg = (int)blockIdx.x & 63;
  const int m0 = rg * 64, u0 = cg * 16;

  const int arow = lane & 15;
  const int ahi = lane >> 4;            // 0..3
  const int rx = arow & 7;              // A-read swizzle key (same for both m-tiles)
  const int erow = tid >> 2, eul = (tid & 3) * 4;   // elementwise mapping

  // ---- load Wh B-fragments into registers: wh[k][ns], 256 VGPRs ----
  bf16x8 wh[32][2];
  {
    const unsigned short* base = whp2 + (size_t)(cg * 2 + wn) * (2 * 32 * 64 * 8);
#pragma unroll
    for (int ns = 0; ns < 2; ns++)
#pragma unroll
      for (int k = 0; k < 32; k++)
        wh[k][ns] = *(const bf16x8*)(base + ((size_t)(ns * 32 + k) * 64 + lane) * 8);
  }

  const char* a0base = (const char*)sA + (size_t)(wm * 32 + arow) * 2048;
  const char* a1base = a0base + 16 * 2048;

  for (int ts = 0; ts < TC_; ts++) {
    const int t = t0 + ts;
    // ---- wait until h(t) fully written by all same-rg blocks ----
    if (t > 0) {
      if (tid == 0) {
        while (__hip_atomic_load(cnt + (size_t)t * RG_ + rg, __ATOMIC_ACQUIRE, __HIP_MEMORY_SCOPE_AGENT) < CG_) {}
      }
      __syncthreads();
    }
    const unsigned short* hsrc = hbuf + (size_t)(t & 1) * (B_ * U_) + (size_t)m0 * U_;

    // ---- stage h rows [m0,m0+64) into sA (16B-slot XOR swizzle slot^(row&7)) ----
#pragma unroll
    for (int i = 0; i < 16; i++) {          // half 0: slots 0..63
      int r = i * 4 + w;
      gload16(hsrc + (size_t)r * U_ + ((lane ^ (r & 7)) << 3),
              (char*)sA + (size_t)r * 2048);
    }
    __syncthreads();                         // half0 landed (vmcnt drained)
#pragma unroll
    for (int i = 0; i < 16; i++) {          // half 1: slots 64..127
      int r = i * 4 + w;
      gload16(hsrc + (size_t)r * U_ + (((64 + lane) ^ (r & 7)) << 3),
              (char*)sA + (size_t)r * 2048 + 1024);
    }

    f32x4 acc[2][2];
#pragma unroll
    for (int i = 0; i < 2; i++) { acc[i][0] = f32x4{0.f,0.f,0.f,0.f}; acc[i][1] = f32x4{0.f,0.f,0.f,0.f}; }

    // ---- compute half 0 (ksteps 0..15) while half 1 is in flight ----
#pragma unroll
    for (int k = 0; k < 16; k++) {
      int gs = k * 4 + ahi;
      bf16x8 a0 = *(const bf16x8*)(a0base + ((gs ^ rx) << 4));
      bf16x8 a1 = *(const bf16x8*)(a1base + ((gs ^ rx) << 4));
      acc[0][0] = __builtin_amdgcn_mfma_f32_16x16x32_bf16(a0, wh[k][0], acc[0][0], 0, 0, 0);
      acc[0][1] = __builtin_amdgcn_mfma_f32_16x16x32_bf16(a0, wh[k][1], acc[0][1], 0, 0, 0);
      acc[1][0] = __builtin_amdgcn_mfma_f32_16x16x32_bf16(a1, wh[k][0], acc[1][0], 0, 0, 0);
      acc[1][1] = __builtin_amdgcn_mfma_f32_16x16x32_bf16(a1, wh[k][1], acc[1][1], 0, 0, 0);
    }
    __syncthreads();                         // half1 landed
    // ---- compute half 1 (ksteps 16..31) ----
#pragma unroll
    for (int k = 16; k < 32; k++) {
      int gs = k * 4 + ahi;
      bf16x8 a0 = *(const bf16x8*)(a0base + ((gs ^ rx) << 4));
      bf16x8 a1 = *(const bf16x8*)(a1base + ((gs ^ rx) << 4));
      acc[0][0] = __builtin_amdgcn_mfma_f32_16x16x32_bf16(a0, wh[k][0], acc[0][0], 0, 0, 0);
      acc[0][1] = __builtin_amdgcn_mfma_f32_16x16x32_bf16(a0, wh[k][1], acc[0][1], 0, 0, 0);
      acc[1][0] = __builtin_amdgcn_mfma_f32_16x16x32_bf16(a1, wh[k][0], acc[1][0], 0, 0, 0);
      acc[1][1] = __builtin_amdgcn_mfma_f32_16x16x32_bf16(a1, wh[k][1], acc[1][1], 0, 0, 0);
    }
    __syncthreads();                         // everyone done reading sA -> safe to alias as sG

    // ---- gate exchange through LDS (C/D: row=(lane>>4)*4+rr, col=lane&15) ----
#pragma unroll
    for (int ms = 0; ms < 2; ms++)
#pragma unroll
      for (int ns = 0; ns < 2; ns++)
#pragma unroll
        for (int rr = 0; rr < 4; rr++)
          sG[wm * 32 + ms * 16 + ahi * 4 + rr][wn * 32 + ns * 16 + arow] = acc[ms][ns][rr];
    __syncthreads();

    // ---- elementwise gate math; thread handles (row=erow, u=eul..eul+3) ----
    {
      const unsigned short* xr = xpc + ((size_t)ts * B_ + (m0 + erow)) * G_ + cg * 64;
      f32x4 vi = *(const f32x4*)&sG[erow][eul];
      f32x4 vf = *(const f32x4*)&sG[erow][16 + eul];
      f32x4 vg = *(const f32x4*)&sG[erow][32 + eul];
      f32x4 vo = *(const f32x4*)&sG[erow][48 + eul];
      us4 xi = *(const us4*)(xr + eul);
      us4 xf = *(const us4*)(xr + 16 + eul);
      us4 xg = *(const us4*)(xr + 32 + eul);
      us4 xo = *(const us4*)(xr + 48 + eul);
      float* cp = cst + (size_t)(m0 + erow) * U_ + u0 + eul;
      float co[4]; *(f32x4*)co = *(const f32x4*)cp;
      float cn[4];
      unsigned long long hv = 0;
#pragma unroll
      for (int j = 0; j < 4; j++) {
        float gi = vi[j] + bf2f(xi[j]);
        float gf = vf[j] + bf2f(xf[j]);
        float gg = vg[j] + bf2f(xg[j]);
        float go = vo[j] + bf2f(xo[j]);
        float cv = sigm_(gf) * co[j] + sigm_(gi) * tanh_(gg);
        cn[j] = cv;
        hv |= (unsigned long long)f2bf(sigm_(go) * tanh_(cv)) << (16 * j);
      }
      *(f32x4*)cp = *(f32x4*)cn;
      unsigned short* hdst = hbuf + (size_t)((t + 1) & 1) * (B_ * U_) + (size_t)(m0 + erow) * U_ + u0 + eul;
      *(unsigned long long*)hdst = hv;
    }
    __syncthreads();                         // all h stores drained (barrier waits vmcnt)
    if (tid == 0) {
      __threadfence();                       // L2 writeback so other XCDs see h(t+1)
      __hip_atomic_fetch_add(cnt + (size_t)(t + 1) * RG_ + rg, 1, __ATOMIC_RELEASE, __HIP_MEMORY_SCOPE_AGENT);
    }
  }
}

// ---------------- head: sigmoid((h@W1+b1)@W2+b2) ----------------
__global__ __launch_bounds__(256) void dense_kernel(
    const unsigned short* __restrict__ h, const float* __restrict__ W1, const float* __restrict__ b1,
    const float* __restrict__ W2, const float* __restrict__ b2, float* __restrict__ out)
{
  int tid = threadIdx.x, j = tid & 63, kq = tid >> 6;
  const unsigned short* hr = h + (size_t)blockIdx.x * U_;
  float s = 0.f;
#pragma unroll 8
  for (int k = kq * 256; k < kq * 256 + 256; k++) s += bf2f(hr[k]) * W1[k * 64 + j];
  __shared__ float red[4][64];
  red[kq][j] = s;
  __syncthreads();
  if (tid < 64) {
    float hid = red[0][j] + red[1][j] + red[2][j] + red[3][j] + b1[j];
    float p = hid * W2[j];
#pragma unroll
    for (int off = 32; off; off >>= 1) p += __shfl_down(p, off, 64);
    if (j == 0) out[blockIdx.x] = 1.f / (1.f + __expf(-(p + b2[0])));
  }
}

extern "C" void kernel_launch(void* const* d_in, const int* in_sizes, int n_in,
                              void* d_out, int out_size, void* d_ws, size_t ws_size,
                              hipStream_t stream) {
  const int*   sent = (const int*)d_in[0];
  const float* emb  = (const float*)d_in[1];
  const float* Wx   = (const float*)d_in[2];
  const float* Wh   = (const float*)d_in[3];
  const float* bias = (const float*)d_in[4];
  const float* W1   = (const float*)d_in[5];
  const float* b1   = (const float*)d_in[6];
  const float* W2   = (const float*)d_in[7];
  const float* b2   = (const float*)d_in[8];
  float* out = (float*)d_out;

  char* ws = (char*)d_ws;
  size_t off = 0;
  auto alloc = [&](size_t bytes) { void* p = ws + off; off += (bytes + 255) & ~(size_t)255; return p; };
  unsigned short* embb = (unsigned short*)alloc((size_t)V_ * E_ * 2);       // 51.2 MB
  unsigned short* wxp  = (unsigned short*)alloc((size_t)E_ * G_ * 2);       // 4.2 MB
  unsigned short* whp2 = (unsigned short*)alloc((size_t)U_ * G_ * 2);       // 8.4 MB
  unsigned short* xpc  = (unsigned short*)alloc((size_t)TC_ * B_ * G_ * 2); // 67 MB
  unsigned short* hbuf = (unsigned short*)alloc((size_t)2 * B_ * U_ * 2);   // 1 MB
  float*          cst  = (float*)alloc((size_t)B_ * U_ * 4);                // 1 MB
  int*            cnt  = (int*)alloc((size_t)(T_ + 1) * RG_ * 4);           // 4 KB

  // prep
  hipLaunchKernelGGL(cvt_bf16_kernel, dim3(12500), dim3(256), 0, stream, emb, embb, (long)V_ * E_);
  hipLaunchKernelGGL(pack_wx_kernel, dim3((E_ / 8) * G_ / 256), dim3(256), 0, stream, Wx, wxp, (E_ / 8) * G_);
  hipLaunchKernelGGL(pack_wh2_kernel, dim3(2048), dim3(256), 0, stream, Wh, whp2);
  hipMemsetAsync(hbuf, 0, (size_t)B_ * U_ * 2, stream);            // h(0) = 0 (buffer 0)
  hipMemsetAsync(cst, 0, (size_t)B_ * U_ * 4, stream);             // c(0) = 0
  hipMemsetAsync(cnt, 0, (size_t)(T_ + 1) * RG_ * 4, stream);      // barrier counters

  for (int ch = 0; ch < NCH_; ch++) {
    hipLaunchKernelGGL(xproj_kernel, dim3(TC_ * B_ / XP_BM, G_ / XP_BN), dim3(256), 0, stream,
                       sent, embb, wxp, bias, xpc, ch * TC_);
    hipLaunchKernelGGL(scan_kernel, dim3(RG_ * CG_), dim3(256), 0, stream,
                       xpc, whp2, hbuf, cst, cnt, ch * TC_);
  }
  hipLaunchKernelGGL(dense_kernel, dim3(B_), dim3(256), 0, stream,
                     hbuf /* h(256) lands in buffer 0 */, W1, b1, W2, b2, out);
}

// Round 3
// 3407.402 us; speedup vs baseline: 2.4227x; 2.4227x over previous
//
#include <hip/hip_runtime.h>

#define B_ 256
#define T_ 256
#define E_ 512
#define U_ 1024
#define G_ 4096   // 4*U
#define V_ 50000
#define TC_ 32    // timesteps per x_proj chunk
#define NCH_ 8    // T_/TC_
#define NG_ 8     // scan groups (one per XCD under %8 round-robin)
#define NS_ 32    // slots (blocks) per group

typedef __bf16 bf16x8 __attribute__((ext_vector_type(8)));
typedef float f32x4 __attribute__((ext_vector_type(4)));
typedef unsigned short us8 __attribute__((ext_vector_type(8)));

__device__ __forceinline__ unsigned short f2bf(float f) {
  union { float f; unsigned u; } v; v.f = f;
  unsigned u = v.u;
  u = (u + 0x7FFFu + ((u >> 16) & 1u)) >> 16;   // RNE
  return (unsigned short)u;
}
__device__ __forceinline__ float bf2f(unsigned short h) {
  union { unsigned u; float f; } v; v.u = ((unsigned)h) << 16;
  return v.f;
}
__device__ __forceinline__ float sigm_(float x) { return 1.f / (1.f + __expf(-x)); }
__device__ __forceinline__ float tanh_(float x) { return 2.f / (1.f + __expf(-2.f * x)) - 1.f; }

__device__ __forceinline__ void gload16(const void* g, void* l) {
  __builtin_amdgcn_global_load_lds((const __attribute__((address_space(1))) void*)g,
                                   (__attribute__((address_space(3))) void*)l, 16, 0, 0);
}

// packed column p = s*128 + gg*32 + ul  ->  original gate column gg*1024 + s*32 + ul
__device__ __forceinline__ int orig_col3(int p) {
  return (((p >> 5) & 3) << 10) + ((p >> 7) << 5) + (p & 31);
}

// ---------------- prep: f32 -> bf16 (row-major) ----------------
__global__ void cvt_bf16_kernel(const float* __restrict__ in, unsigned short* __restrict__ out, long n) {
  long i = (((long)blockIdx.x * blockDim.x) + threadIdx.x) << 3;
  long stride = ((long)gridDim.x * blockDim.x) << 3;
  for (; i < n; i += stride) {
    float4 x = *(const float4*)(in + i);
    float4 y = *(const float4*)(in + i + 4);
    us8 v;
    v[0] = f2bf(x.x); v[1] = f2bf(x.y); v[2] = f2bf(x.z); v[3] = f2bf(x.w);
    v[4] = f2bf(y.x); v[5] = f2bf(y.y); v[6] = f2bf(y.z); v[7] = f2bf(y.w);
    *(us8*)(out + i) = v;
  }
}

// ---------------- prep: pack Wx [K][4096] f32 -> [K/8][4096 packed][8] bf16 ----------------
__global__ void pack_wx_kernel(const float* __restrict__ w, unsigned short* __restrict__ out, int total) {
  int t = blockIdx.x * blockDim.x + threadIdx.x;   // over (K/8)*4096
  if (t >= total) return;
  int kb = t >> 12, n = t & 4095;
  int oc = orig_col3(n);
  us8 v;
#pragma unroll
  for (int ki = 0; ki < 8; ki++) v[ki] = f2bf(w[(size_t)(kb * 8 + ki) * G_ + oc]);
  *(us8*)(out + (size_t)t * 8) = v;
}

// ---------------- prep: pack Wh into scan B-fragment order ----------------
// flat t bits (low->high): [lane:6][nf:1][ks:4][nq:2][kh:1][s:5]
// element i = Wh[kh*512 + ks*32 + (lane>>4)*8 + i][nq*1024 + s*32 + nf*16 + (lane&15)]
__global__ void pack_wh3_kernel(const float* __restrict__ w, unsigned short* __restrict__ out) {
  int t = blockIdx.x * blockDim.x + threadIdx.x;   // 524288 total
  int lane = t & 63;
  int nf = (t >> 6) & 1;
  int ks = (t >> 7) & 15;
  int nq = (t >> 11) & 3;
  int kh = (t >> 13) & 1;
  int s  = t >> 14;
  int k0 = kh * 512 + ks * 32 + (lane >> 4) * 8;
  int oc = nq * 1024 + s * 32 + nf * 16 + (lane & 15);
  us8 v;
#pragma unroll
  for (int i = 0; i < 8; i++) v[i] = f2bf(w[(size_t)(k0 + i) * G_ + oc]);
  *(us8*)(out + (size_t)t * 8) = v;
}

// ---------------- x_proj: gather(emb) @ Wx + b -> bf16 [TC*B][G packed] ----------------
#define XP_BM 128
#define XP_BN 128
#define XP_KC 64
__global__ __launch_bounds__(256, 2) void xproj_kernel(
    const int* __restrict__ sent, const unsigned short* __restrict__ embb,
    const unsigned short* __restrict__ wxp, const float* __restrict__ bias,
    unsigned short* __restrict__ xp, int t0)
{
  __shared__ __align__(16) unsigned short sA[2][XP_BM * XP_KC];
  __shared__ __align__(16) unsigned short sB[2][XP_KC * XP_BN];
  __shared__ int tok[XP_BM];

  const int tid = threadIdx.x;
  const int lane = tid & 63;
  const int wid = tid >> 6;
  const int m0 = blockIdx.x * XP_BM;
  const int n0 = blockIdx.y * XP_BN;

  if (tid < XP_BM) {
    int row = m0 + tid;
    int tl = row >> 8, b = row & 255;
    tok[tid] = sent[b * T_ + t0 + tl];
  }
  __syncthreads();

  auto stageA = [&](int bf, int kc) {
#pragma unroll
    for (int ii = 0; ii < 4; ii++) {
      int i = wid * 4 + ii;
      int m = i * 8 + (lane >> 3);
      int cl = lane & 7;
      const unsigned short* src = embb + (size_t)tok[m] * E_ + kc + ((cl ^ (m & 7)) << 3);
      gload16(src, &sA[bf][i * 512]);
    }
  };
  auto stageB = [&](int bf, int kc) {
    int kb0 = kc >> 3;
#pragma unroll
    for (int jj = 0; jj < 4; jj++) {
      int j = wid * 4 + jj;
      int r = j >> 1;
      int nl = ((j & 1) << 6) + lane;
      int n = nl ^ r;
      const unsigned short* src = wxp + ((size_t)(kb0 + r) * G_ + n0 + n) * 8;
      gload16(src, &sB[bf][j * 512]);
    }
  };

  f32x4 acc[4][4];
#pragma unroll
  for (int i = 0; i < 4; i++)
#pragma unroll
    for (int j = 0; j < 4; j++) acc[i][j] = f32x4{0.f, 0.f, 0.f, 0.f};

  const int wm = wid >> 1, wn = wid & 1;

  stageA(0, 0); stageB(0, 0);
  for (int it = 0; it < E_ / XP_KC; it++) {   // 8
    int bf = it & 1;
    __syncthreads();
    if (it < E_ / XP_KC - 1) { stageA(bf ^ 1, (it + 1) * XP_KC); stageB(bf ^ 1, (it + 1) * XP_KC); }
#pragma unroll
    for (int kk = 0; kk < 2; kk++) {
      int c = (kk << 2) + (lane >> 4);
      bf16x8 a[4], b[4];
#pragma unroll
      for (int ms = 0; ms < 4; ms++) {
        int m = (wm << 6) + (ms << 4) + (lane & 15);
        a[ms] = *(const bf16x8*)&sA[bf][m * 64 + ((c ^ (m & 7)) << 3)];
      }
#pragma unroll
      for (int ns = 0; ns < 4; ns++) {
        int n = (wn << 6) + (ns << 4) + (lane & 15);
        b[ns] = *(const bf16x8*)&sB[bf][((c << 7) + (n ^ c)) << 3];
      }
#pragma unroll
      for (int ms = 0; ms < 4; ms++)
#pragma unroll
        for (int ns = 0; ns < 4; ns++)
          acc[ms][ns] = __builtin_amdgcn_mfma_f32_16x16x32_bf16(a[ms], b[ns], acc[ms][ns], 0, 0, 0);
    }
  }

#pragma unroll
  for (int ns = 0; ns < 4; ns++) {
    int col = n0 + (wn << 6) + (ns << 4) + (lane & 15);
    float bv = bias[orig_col3(col)];
#pragma unroll
    for (int ms = 0; ms < 4; ms++) {
      int rbase = m0 + (wm << 6) + (ms << 4) + ((lane >> 4) << 2);
#pragma unroll
      for (int rr = 0; rr < 4; rr++)
        xp[(size_t)(rbase + rr) * G_ + col] = f2bf(acc[ms][ns][rr] + bv);
    }
  }
}

// ---------------- persistent scan: batch-partitioned, XCD-local ----------------
// grid 256: block b -> group g=b&7 (rows g*32..g*32+32), slot s=b>>3 (u-cols s*32..s*32+32)
// 512 threads = 8 waves: wave w -> kh=w>>2 (K-half of 512), nq=w&3 (gate quarter = gate nq)
__global__ __launch_bounds__(512, 2) void scan_kernel(
    const unsigned short* __restrict__ xpc,   // [TC][256][4096 packed] bf16 (bias incl.)
    const unsigned short* __restrict__ whp3,  // packed Wh B-fragments
    unsigned short* __restrict__ hbuf,        // [2][256][1024] bf16
    float* __restrict__ cst,                  // [256][1024] f32
    int* __restrict__ cnt,                    // [T+1][NG] arrival counters
    int t0)
{
  __shared__ __align__(16) unsigned short sA[32 * 1024];   // 64KB: h rows, swizzled 16B slots
  __shared__ float sG[4][32][33];                           // kh=0 partials / final gates
  __shared__ float sP[4][32][33];                           // kh=1 partials

  const int tid = threadIdx.x, lane = tid & 63, w = tid >> 6;
  const int kh = w >> 2, nq = w & 3;
  const int g = (int)blockIdx.x & 7, s = (int)blockIdx.x >> 3;
  const int m0g = g * 32;          // global batch row base
  const int u0 = s * 32;           // u base
  const int rx = lane & 7;         // A-read swizzle key (row&7 of lane&15, mt-invariant)

  // ---- Wh B-fragments in registers: 32 x bf16x8 = 128 VGPR ----
  bf16x8 wh[16][2];
  {
    const bf16x8* wb = (const bf16x8*)whp3 +
        (((((size_t)s * 2 + kh) * 4 + nq) * 16) * 2) * 64;   // [ks][nf][lane]
#pragma unroll
    for (int ks = 0; ks < 16; ks++)
#pragma unroll
      for (int nf = 0; nf < 2; nf++)
        wh[ks][nf] = wb[(ks * 2 + nf) * 64 + lane];
  }

  // ---- c-state in registers (2 elems per thread) ----
  const int r_e = tid >> 4, ue = (tid & 15) * 2;
  const size_t ci = (size_t)(m0g + r_e) * U_ + u0 + ue;
  float c0v = cst[ci], c1v = cst[ci + 1];

  const char* sAb = (const char*)sA;
  const char* abase0 = sAb + (size_t)(lane & 15) * 2048 + kh * 1024;
  const char* abase1 = abase0 + 16 * 2048;

  for (int ts = 0; ts < TC_; ts++) {
    const int t = t0 + ts;
    // ---- wait for h(t): relaxed poll + one acquire fence ----
    if (t > 0) {
      if (tid == 0) {
        const int* cp = cnt + (size_t)t * NG_ + g;
        while (__hip_atomic_load(cp, __ATOMIC_RELAXED, __HIP_MEMORY_SCOPE_AGENT) < NS_) {}
        __builtin_amdgcn_fence(__ATOMIC_ACQUIRE, "agent");
      }
      __syncthreads();
    }

    // ---- stage h rows [m0g, m0g+32) x 1024 into sA (64 wave-issues; 8 per wave) ----
    const unsigned short* hsrc = hbuf + (size_t)(t & 1) * (B_ * U_) + (size_t)m0g * U_;
#pragma unroll
    for (int jj = 0; jj < 8; jj++) {
      int j = w * 8 + jj;
      int r = j >> 1, kh2 = j & 1;
      gload16(hsrc + (size_t)r * U_ + (((kh2 << 6) | (lane ^ (r & 7))) << 3),
              &sA[r * 1024 + kh2 * 512]);
    }
    __syncthreads();                         // sA ready (vmcnt drained)

    // ---- GEMM: [32 rows] x [128 gate-cols quarter] over K-half 512 ----
    f32x4 acc[2][2];
#pragma unroll
    for (int i = 0; i < 2; i++) { acc[i][0] = f32x4{0.f,0.f,0.f,0.f}; acc[i][1] = f32x4{0.f,0.f,0.f,0.f}; }
#pragma unroll
    for (int ks = 0; ks < 16; ks++) {
      int c = ks * 4 + (lane >> 4);          // 16B slot within K-half
      bf16x8 a0 = *(const bf16x8*)(abase0 + ((c ^ rx) << 4));
      bf16x8 a1 = *(const bf16x8*)(abase1 + ((c ^ rx) << 4));
      acc[0][0] = __builtin_amdgcn_mfma_f32_16x16x32_bf16(a0, wh[ks][0], acc[0][0], 0, 0, 0);
      acc[0][1] = __builtin_amdgcn_mfma_f32_16x16x32_bf16(a0, wh[ks][1], acc[0][1], 0, 0, 0);
      acc[1][0] = __builtin_amdgcn_mfma_f32_16x16x32_bf16(a1, wh[ks][0], acc[1][0], 0, 0, 0);
      acc[1][1] = __builtin_amdgcn_mfma_f32_16x16x32_bf16(a1, wh[ks][1], acc[1][1], 0, 0, 0);
    }

    // ---- write K-half partials (kh=0 -> sG, kh=1 -> sP) ----
    {
      float (*sOut)[32][33] = kh ? sP : sG;
#pragma unroll
      for (int mt = 0; mt < 2; mt++)
#pragma unroll
        for (int nf = 0; nf < 2; nf++)
#pragma unroll
          for (int rr = 0; rr < 4; rr++)
            sOut[nq][mt * 16 + (lane >> 4) * 4 + rr][nf * 16 + (lane & 15)] = acc[mt][nf][rr];
    }
    __syncthreads();

    // ---- elementwise gate math: thread -> (row r_e, u = ue, ue+1) ----
    {
      const unsigned short* xr = xpc + ((size_t)ts * B_ + (m0g + r_e)) * G_ + s * 128;
      float cn[2]; unsigned hv = 0;
#pragma unroll
      for (int j = 0; j < 2; j++) {
        int u = ue + j;
        float gi = sG[0][r_e][u] + sP[0][r_e][u] + bf2f(xr[u]);
        float gf = sG[1][r_e][u] + sP[1][r_e][u] + bf2f(xr[32 + u]);
        float gg = sG[2][r_e][u] + sP[2][r_e][u] + bf2f(xr[64 + u]);
        float go = sG[3][r_e][u] + sP[3][r_e][u] + bf2f(xr[96 + u]);
        float co = j ? c1v : c0v;
        float cv = sigm_(gf) * co + sigm_(gi) * tanh_(gg);
        cn[j] = cv;
        hv |= (unsigned)f2bf(sigm_(go) * tanh_(cv)) << (16 * j);
      }
      c0v = cn[0]; c1v = cn[1];
      unsigned short* hdst = hbuf + (size_t)((t + 1) & 1) * (B_ * U_) + ci;
      *(unsigned*)hdst = hv;
    }
    __syncthreads();                         // h stores drained (barrier implies vmcnt 0)
    if (tid == 0)
      __hip_atomic_fetch_add(cnt + (size_t)(t + 1) * NG_ + g, 1, __ATOMIC_RELEASE, __HIP_MEMORY_SCOPE_AGENT);
  }

  cst[ci] = c0v; cst[ci + 1] = c1v;
}

// ---------------- head: sigmoid((h@W1+b1)@W2+b2) ----------------
__global__ __launch_bounds__(256) void dense_kernel(
    const unsigned short* __restrict__ h, const float* __restrict__ W1, const float* __restrict__ b1,
    const float* __restrict__ W2, const float* __restrict__ b2, float* __restrict__ out)
{
  int tid = threadIdx.x, j = tid & 63, kq = tid >> 6;
  const unsigned short* hr = h + (size_t)blockIdx.x * U_;
  float s = 0.f;
#pragma unroll 8
  for (int k = kq * 256; k < kq * 256 + 256; k++) s += bf2f(hr[k]) * W1[k * 64 + j];
  __shared__ float red[4][64];
  red[kq][j] = s;
  __syncthreads();
  if (tid < 64) {
    float hid = red[0][j] + red[1][j] + red[2][j] + red[3][j] + b1[j];
    float p = hid * W2[j];
#pragma unroll
    for (int off = 32; off; off >>= 1) p += __shfl_down(p, off, 64);
    if (j == 0) out[blockIdx.x] = 1.f / (1.f + __expf(-(p + b2[0])));
  }
}

extern "C" void kernel_launch(void* const* d_in, const int* in_sizes, int n_in,
                              void* d_out, int out_size, void* d_ws, size_t ws_size,
                              hipStream_t stream) {
  const int*   sent = (const int*)d_in[0];
  const float* emb  = (const float*)d_in[1];
  const float* Wx   = (const float*)d_in[2];
  const float* Wh   = (const float*)d_in[3];
  const float* bias = (const float*)d_in[4];
  const float* W1   = (const float*)d_in[5];
  const float* b1   = (const float*)d_in[6];
  const float* W2   = (const float*)d_in[7];
  const float* b2   = (const float*)d_in[8];
  float* out = (float*)d_out;

  char* ws = (char*)d_ws;
  size_t off = 0;
  auto alloc = [&](size_t bytes) { void* p = ws + off; off += (bytes + 255) & ~(size_t)255; return p; };
  unsigned short* embb = (unsigned short*)alloc((size_t)V_ * E_ * 2);       // 51.2 MB
  unsigned short* wxp  = (unsigned short*)alloc((size_t)E_ * G_ * 2);       // 4.2 MB
  unsigned short* whp3 = (unsigned short*)alloc((size_t)U_ * G_ * 2);       // 8.4 MB
  unsigned short* xpc  = (unsigned short*)alloc((size_t)TC_ * B_ * G_ * 2); // 67 MB
  unsigned short* hbuf = (unsigned short*)alloc((size_t)2 * B_ * U_ * 2);   // 1 MB
  float*          cst  = (float*)alloc((size_t)B_ * U_ * 4);                // 1 MB
  int*            cnt  = (int*)alloc((size_t)(T_ + 1) * NG_ * 4);           // 8.3 KB

  // prep
  hipLaunchKernelGGL(cvt_bf16_kernel, dim3(12500), dim3(256), 0, stream, emb, embb, (long)V_ * E_);
  hipLaunchKernelGGL(pack_wx_kernel, dim3((E_ / 8) * G_ / 256), dim3(256), 0, stream, Wx, wxp, (E_ / 8) * G_);
  hipLaunchKernelGGL(pack_wh3_kernel, dim3(2048), dim3(256), 0, stream, Wh, whp3);
  hipMemsetAsync(hbuf, 0, (size_t)B_ * U_ * 2, stream);            // h(0) = 0 (buffer 0)
  hipMemsetAsync(cst, 0, (size_t)B_ * U_ * 4, stream);             // c(0) = 0
  hipMemsetAsync(cnt, 0, (size_t)(T_ + 1) * NG_ * 4, stream);      // barrier counters

  for (int ch = 0; ch < NCH_; ch++) {
    hipLaunchKernelGGL(xproj_kernel, dim3(TC_ * B_ / XP_BM, G_ / XP_BN), dim3(256), 0, stream,
                       sent, embb, wxp, bias, xpc, ch * TC_);
    hipLaunchKernelGGL(scan_kernel, dim3(NG_ * NS_), dim3(512), 0, stream,
                       xpc, whp3, hbuf, cst, cnt, ch * TC_);
  }
  hipLaunchKernelGGL(dense_kernel, dim3(B_), dim3(256), 0, stream,
                     hbuf /* h(256) lands in buffer 0 */, W1, b1, W2, b2, out);
}

// Round 4
// 1657.132 us; speedup vs baseline: 4.9817x; 2.0562x over previous
//
#include <hip/hip_runtime.h>

#define B_ 256
#define T_ 256
#define E_ 512
#define U_ 1024
#define G_ 4096   // 4*U
#define V_ 50000
#define TC_ 32    // timesteps per x_proj chunk
#define NCH_ 8    // T_/TC_
#define NG_ 8     // scan groups (one per XCD under %8 round-robin)
#define NS_ 32    // slots (blocks) per group
#define CPAD_ 32  // ints per counter slot (128B line padding)

typedef __bf16 bf16x8 __attribute__((ext_vector_type(8)));
typedef float f32x4 __attribute__((ext_vector_type(4)));
typedef unsigned short us8 __attribute__((ext_vector_type(8)));
typedef unsigned long long u64x2 __attribute__((ext_vector_type(2)));

__device__ __forceinline__ unsigned short f2bf(float f) {
  union { float f; unsigned u; } v; v.f = f;
  unsigned u = v.u;
  u = (u + 0x7FFFu + ((u >> 16) & 1u)) >> 16;   // RNE
  return (unsigned short)u;
}
__device__ __forceinline__ float bf2f(unsigned short h) {
  union { unsigned u; float f; } v; v.u = ((unsigned)h) << 16;
  return v.f;
}
__device__ __forceinline__ float sigm_(float x) { return 1.f / (1.f + __expf(-x)); }
__device__ __forceinline__ float tanh_(float x) { return 2.f / (1.f + __expf(-2.f * x)) - 1.f; }

__device__ __forceinline__ void gload16(const void* g, void* l) {
  __builtin_amdgcn_global_load_lds((const __attribute__((address_space(1))) void*)g,
                                   (__attribute__((address_space(3))) void*)l, 16, 0, 0);
}

// packed column p = s*128 + gg*32 + ul  ->  original gate column gg*1024 + s*32 + ul
__device__ __forceinline__ int orig_col3(int p) {
  return (((p >> 5) & 3) << 10) + ((p >> 7) << 5) + (p & 31);
}

// ---------------- prep: f32 -> bf16 (row-major) ----------------
__global__ void cvt_bf16_kernel(const float* __restrict__ in, unsigned short* __restrict__ out, long n) {
  long i = (((long)blockIdx.x * blockDim.x) + threadIdx.x) << 3;
  long stride = ((long)gridDim.x * blockDim.x) << 3;
  for (; i < n; i += stride) {
    float4 x = *(const float4*)(in + i);
    float4 y = *(const float4*)(in + i + 4);
    us8 v;
    v[0] = f2bf(x.x); v[1] = f2bf(x.y); v[2] = f2bf(x.z); v[3] = f2bf(x.w);
    v[4] = f2bf(y.x); v[5] = f2bf(y.y); v[6] = f2bf(y.z); v[7] = f2bf(y.w);
    *(us8*)(out + i) = v;
  }
}

// ---------------- prep: pack Wx [K][4096] f32 -> [K/8][4096 packed][8] bf16 ----------------
__global__ void pack_wx_kernel(const float* __restrict__ w, unsigned short* __restrict__ out, int total) {
  int t = blockIdx.x * blockDim.x + threadIdx.x;   // over (K/8)*4096
  if (t >= total) return;
  int kb = t >> 12, n = t & 4095;
  int oc = orig_col3(n);
  us8 v;
#pragma unroll
  for (int ki = 0; ki < 8; ki++) v[ki] = f2bf(w[(size_t)(kb * 8 + ki) * G_ + oc]);
  *(us8*)(out + (size_t)t * 8) = v;
}

// ---------------- prep: pack Wh into scan B-fragment order ----------------
// flat t bits (low->high): [lane:6][nf:1][ks:4][nq:2][kh:1][s:5]
// element i = Wh[kh*512 + ks*32 + (lane>>4)*8 + i][nq*1024 + s*32 + nf*16 + (lane&15)]
__global__ void pack_wh3_kernel(const float* __restrict__ w, unsigned short* __restrict__ out) {
  int t = blockIdx.x * blockDim.x + threadIdx.x;   // 524288 total
  int lane = t & 63;
  int nf = (t >> 6) & 1;
  int ks = (t >> 7) & 15;
  int nq = (t >> 11) & 3;
  int kh = (t >> 13) & 1;
  int s  = t >> 14;
  int k0 = kh * 512 + ks * 32 + (lane >> 4) * 8;
  int oc = nq * 1024 + s * 32 + nf * 16 + (lane & 15);
  us8 v;
#pragma unroll
  for (int i = 0; i < 8; i++) v[i] = f2bf(w[(size_t)(k0 + i) * G_ + oc]);
  *(us8*)(out + (size_t)t * 8) = v;
}

// ---------------- x_proj: gather(emb) @ Wx + b -> bf16 [TC*B][G packed] ----------------
#define XP_BM 128
#define XP_BN 128
#define XP_KC 64
__global__ __launch_bounds__(256, 2) void xproj_kernel(
    const int* __restrict__ sent, const unsigned short* __restrict__ embb,
    const unsigned short* __restrict__ wxp, const float* __restrict__ bias,
    unsigned short* __restrict__ xp, int t0)
{
  __shared__ __align__(16) unsigned short sA[2][XP_BM * XP_KC];
  __shared__ __align__(16) unsigned short sB[2][XP_KC * XP_BN];
  __shared__ int tok[XP_BM];

  const int tid = threadIdx.x;
  const int lane = tid & 63;
  const int wid = tid >> 6;
  const int m0 = blockIdx.x * XP_BM;
  const int n0 = blockIdx.y * XP_BN;

  if (tid < XP_BM) {
    int row = m0 + tid;
    int tl = row >> 8, b = row & 255;
    tok[tid] = sent[b * T_ + t0 + tl];
  }
  __syncthreads();

  auto stageA = [&](int bf, int kc) {
#pragma unroll
    for (int ii = 0; ii < 4; ii++) {
      int i = wid * 4 + ii;
      int m = i * 8 + (lane >> 3);
      int cl = lane & 7;
      const unsigned short* src = embb + (size_t)tok[m] * E_ + kc + ((cl ^ (m & 7)) << 3);
      gload16(src, &sA[bf][i * 512]);
    }
  };
  auto stageB = [&](int bf, int kc) {
    int kb0 = kc >> 3;
#pragma unroll
    for (int jj = 0; jj < 4; jj++) {
      int j = wid * 4 + jj;
      int r = j >> 1;
      int nl = ((j & 1) << 6) + lane;
      int n = nl ^ r;
      const unsigned short* src = wxp + ((size_t)(kb0 + r) * G_ + n0 + n) * 8;
      gload16(src, &sB[bf][j * 512]);
    }
  };

  f32x4 acc[4][4];
#pragma unroll
  for (int i = 0; i < 4; i++)
#pragma unroll
    for (int j = 0; j < 4; j++) acc[i][j] = f32x4{0.f, 0.f, 0.f, 0.f};

  const int wm = wid >> 1, wn = wid & 1;

  stageA(0, 0); stageB(0, 0);
  for (int it = 0; it < E_ / XP_KC; it++) {   // 8
    int bf = it & 1;
    __syncthreads();
    if (it < E_ / XP_KC - 1) { stageA(bf ^ 1, (it + 1) * XP_KC); stageB(bf ^ 1, (it + 1) * XP_KC); }
#pragma unroll
    for (int kk = 0; kk < 2; kk++) {
      int c = (kk << 2) + (lane >> 4);
      bf16x8 a[4], b[4];
#pragma unroll
      for (int ms = 0; ms < 4; ms++) {
        int m = (wm << 6) + (ms << 4) + (lane & 15);
        a[ms] = *(const bf16x8*)&sA[bf][m * 64 + ((c ^ (m & 7)) << 3)];
      }
#pragma unroll
      for (int ns = 0; ns < 4; ns++) {
        int n = (wn << 6) + (ns << 4) + (lane & 15);
        b[ns] = *(const bf16x8*)&sB[bf][((c << 7) + (n ^ c)) << 3];
      }
#pragma unroll
      for (int ms = 0; ms < 4; ms++)
#pragma unroll
        for (int ns = 0; ns < 4; ns++)
          acc[ms][ns] = __builtin_amdgcn_mfma_f32_16x16x32_bf16(a[ms], b[ns], acc[ms][ns], 0, 0, 0);
    }
  }

#pragma unroll
  for (int ns = 0; ns < 4; ns++) {
    int col = n0 + (wn << 6) + (ns << 4) + (lane & 15);
    float bv = bias[orig_col3(col)];
#pragma unroll
    for (int ms = 0; ms < 4; ms++) {
      int rbase = m0 + (wm << 6) + (ms << 4) + ((lane >> 4) << 2);
#pragma unroll
      for (int rr = 0; rr < 4; rr++)
        xp[(size_t)(rbase + rr) * G_ + col] = f2bf(acc[ms][ns][rr] + bv);
    }
  }
}

// ---------------- persistent scan: batch-partitioned, fence-free sc1 protocol ----------------
// grid 256: block b -> group g=b&7 (rows g*32..g*32+32), slot s=b>>3 (u-cols s*32..s*32+32)
// 512 threads = 8 waves: wave w -> kh=w>>2 (K-half of 512), nq=w&3 (gate quarter)
__global__ __launch_bounds__(512, 2) void scan_kernel(
    const unsigned short* __restrict__ xpc,   // [TC][256][4096 packed] bf16 (bias incl.)
    const unsigned short* __restrict__ whp3,  // packed Wh B-fragments
    unsigned short* __restrict__ hbuf,        // [2][256][1024] bf16
    float* __restrict__ cst,                  // [256][1024] f32
    int* __restrict__ cnt,                    // [T+1][NG] arrival counters, 128B-padded
    int t0)
{
  __shared__ __align__(16) unsigned short sA[32 * 1024];   // 64KB: h rows, swizzled 16B slots
  __shared__ float sG[4][32][33];                           // kh=0 partials
  __shared__ float sP[4][32][33];                           // kh=1 partials

  const int tid = threadIdx.x, lane = tid & 63, w = tid >> 6;
  const int kh = w >> 2, nq = w & 3;
  const int g = (int)blockIdx.x & 7, s = (int)blockIdx.x >> 3;
  const int m0g = g * 32;          // global batch row base
  const int u0 = s * 32;           // u base
  const int rx = lane & 7;         // A-read swizzle key ((lane&15)&7)

  // ---- Wh B-fragments in registers: 32 x bf16x8 = 128 regs ----
  bf16x8 wh[16][2];
  {
    const bf16x8* wb = (const bf16x8*)whp3 +
        (((((size_t)s * 2 + kh) * 4 + nq) * 16) * 2) * 64;   // [ks][nf][lane]
#pragma unroll
    for (int ks = 0; ks < 16; ks++)
#pragma unroll
      for (int nf = 0; nf < 2; nf++)
        wh[ks][nf] = wb[(ks * 2 + nf) * 64 + lane];
  }

  // ---- c-state in registers (2 elems per thread) ----
  const int r_e = tid >> 4, ue = (tid & 15) * 2;
  const size_t ci = (size_t)(m0g + r_e) * U_ + u0 + ue;
  float c0v = cst[ci], c1v = cst[ci + 1];

  // staging mapping: thread covers 16B chunk (r, sc) for r = j*4 + sr0
  const int sr0 = tid >> 7;        // 0..3
  const int sc = tid & 127;        // 16B-chunk within row (128 per row)

  const char* sAb = (const char*)sA;
  const char* abase0 = sAb + (size_t)(lane & 15) * 2048 + kh * 1024;
  const char* abase1 = abase0 + 16 * 2048;

  for (int ts = 0; ts < TC_; ts++) {
    const int t = t0 + ts;
    // ---- wait for h(t): relaxed agent poll, no fences ----
    if (t > 0) {
      if (tid == 0) {
        int* cp = cnt + (size_t)(t * NG_ + g) * CPAD_;
        while (__hip_atomic_load(cp, __ATOMIC_RELAXED, __HIP_MEMORY_SCOPE_AGENT) < NS_) {}
      }
      __syncthreads();
    }

    // ---- stage h rows [m0g, m0g+32) x 1024 into sA via sc1 loads + swizzled ds_write ----
    const unsigned short* hsrc = hbuf + (size_t)(t & 1) * (B_ * U_) + (size_t)m0g * U_;
#pragma unroll
    for (int jj = 0; jj < 2; jj++) {
      unsigned long long hv[4][2];
#pragma unroll
      for (int j = 0; j < 4; j++) {
        int r = (jj * 4 + j) * 4 + sr0;
        unsigned long long* p = (unsigned long long*)(hsrc + (size_t)r * U_ + sc * 8);
        hv[j][0] = __hip_atomic_load(p, __ATOMIC_RELAXED, __HIP_MEMORY_SCOPE_AGENT);
        hv[j][1] = __hip_atomic_load(p + 1, __ATOMIC_RELAXED, __HIP_MEMORY_SCOPE_AGENT);
      }
#pragma unroll
      for (int j = 0; j < 4; j++) {
        int r = (jj * 4 + j) * 4 + sr0;
        u64x2 v; v[0] = hv[j][0]; v[1] = hv[j][1];
        *(u64x2*)((char*)sAb + (size_t)r * 2048 + ((sc ^ (r & 7)) << 4)) = v;
      }
    }
    __syncthreads();                         // sA ready

    // ---- GEMM: [32 rows] x [128 gate-cols quarter] over K-half 512 ----
    f32x4 acc[2][2];
#pragma unroll
    for (int i = 0; i < 2; i++) { acc[i][0] = f32x4{0.f,0.f,0.f,0.f}; acc[i][1] = f32x4{0.f,0.f,0.f,0.f}; }
#pragma unroll
    for (int ks = 0; ks < 16; ks++) {
      int c = ks * 4 + (lane >> 4);          // 16B slot within K-half
      bf16x8 a0 = *(const bf16x8*)(abase0 + ((c ^ rx) << 4));
      bf16x8 a1 = *(const bf16x8*)(abase1 + ((c ^ rx) << 4));
      acc[0][0] = __builtin_amdgcn_mfma_f32_16x16x32_bf16(a0, wh[ks][0], acc[0][0], 0, 0, 0);
      acc[0][1] = __builtin_amdgcn_mfma_f32_16x16x32_bf16(a0, wh[ks][1], acc[0][1], 0, 0, 0);
      acc[1][0] = __builtin_amdgcn_mfma_f32_16x16x32_bf16(a1, wh[ks][0], acc[1][0], 0, 0, 0);
      acc[1][1] = __builtin_amdgcn_mfma_f32_16x16x32_bf16(a1, wh[ks][1], acc[1][1], 0, 0, 0);
    }

    // ---- prefetch xpc gate addends (HBM latency hides under LDS exchange) ----
    const unsigned short* xr = xpc + ((size_t)ts * B_ + (m0g + r_e)) * G_ + s * 128;
    unsigned xiv = *(const unsigned*)(xr + ue);
    unsigned xfv = *(const unsigned*)(xr + 32 + ue);
    unsigned xgv = *(const unsigned*)(xr + 64 + ue);
    unsigned xov = *(const unsigned*)(xr + 96 + ue);

    // ---- write K-half partials (kh=0 -> sG, kh=1 -> sP) ----
    {
      float (*sOut)[32][33] = kh ? sP : sG;
#pragma unroll
      for (int mt = 0; mt < 2; mt++)
#pragma unroll
        for (int nf = 0; nf < 2; nf++)
#pragma unroll
          for (int rr = 0; rr < 4; rr++)
            sOut[nq][mt * 16 + (lane >> 4) * 4 + rr][nf * 16 + (lane & 15)] = acc[mt][nf][rr];
    }
    __syncthreads();

    // ---- elementwise gate math: thread -> (row r_e, u = ue, ue+1) ----
    {
      float cn[2]; unsigned hv = 0;
#pragma unroll
      for (int j = 0; j < 2; j++) {
        int u = ue + j;
        float gi = sG[0][r_e][u] + sP[0][r_e][u] + bf2f((unsigned short)(j ? (xiv >> 16) : xiv));
        float gf = sG[1][r_e][u] + sP[1][r_e][u] + bf2f((unsigned short)(j ? (xfv >> 16) : xfv));
        float gg = sG[2][r_e][u] + sP[2][r_e][u] + bf2f((unsigned short)(j ? (xgv >> 16) : xgv));
        float go = sG[3][r_e][u] + sP[3][r_e][u] + bf2f((unsigned short)(j ? (xov >> 16) : xov));
        float co = j ? c1v : c0v;
        float cv = sigm_(gf) * co + sigm_(gi) * tanh_(gg);
        cn[j] = cv;
        hv |= (unsigned)f2bf(sigm_(go) * tanh_(cv)) << (16 * j);
      }
      c0v = cn[0]; c1v = cn[1];
      unsigned* hdst = (unsigned*)(hbuf + (size_t)((t + 1) & 1) * (B_ * U_) + ci);
      __hip_atomic_store(hdst, hv, __ATOMIC_RELAXED, __HIP_MEMORY_SCOPE_AGENT);
    }
    __syncthreads();                         // drains vmcnt: all sc1 h-stores retired/visible
    if (tid == 0)
      __hip_atomic_fetch_add(cnt + (size_t)((t + 1) * NG_ + g) * CPAD_, 1,
                             __ATOMIC_RELAXED, __HIP_MEMORY_SCOPE_AGENT);
  }

  cst[ci] = c0v; cst[ci + 1] = c1v;   // plain: kernel-boundary release covers next dispatch
}

// ---------------- head: sigmoid((h@W1+b1)@W2+b2) ----------------
__global__ __launch_bounds__(256) void dense_kernel(
    const unsigned short* __restrict__ h, const float* __restrict__ W1, const float* __restrict__ b1,
    const float* __restrict__ W2, const float* __restrict__ b2, float* __restrict__ out)
{
  int tid = threadIdx.x, j = tid & 63, kq = tid >> 6;
  const unsigned short* hr = h + (size_t)blockIdx.x * U_;
  float s = 0.f;
#pragma unroll 8
  for (int k = kq * 256; k < kq * 256 + 256; k++) s += bf2f(hr[k]) * W1[k * 64 + j];
  __shared__ float red[4][64];
  red[kq][j] = s;
  __syncthreads();
  if (tid < 64) {
    float hid = red[0][j] + red[1][j] + red[2][j] + red[3][j] + b1[j];
    float p = hid * W2[j];
#pragma unroll
    for (int off = 32; off; off >>= 1) p += __shfl_down(p, off, 64);
    if (j == 0) out[blockIdx.x] = 1.f / (1.f + __expf(-(p + b2[0])));
  }
}

extern "C" void kernel_launch(void* const* d_in, const int* in_sizes, int n_in,
                              void* d_out, int out_size, void* d_ws, size_t ws_size,
                              hipStream_t stream) {
  const int*   sent = (const int*)d_in[0];
  const float* emb  = (const float*)d_in[1];
  const float* Wx   = (const float*)d_in[2];
  const float* Wh   = (const float*)d_in[3];
  const float* bias = (const float*)d_in[4];
  const float* W1   = (const float*)d_in[5];
  const float* b1   = (const float*)d_in[6];
  const float* W2   = (const float*)d_in[7];
  const float* b2   = (const float*)d_in[8];
  float* out = (float*)d_out;

  char* ws = (char*)d_ws;
  size_t off = 0;
  auto alloc = [&](size_t bytes) { void* p = ws + off; off += (bytes + 255) & ~(size_t)255; return p; };
  unsigned short* embb = (unsigned short*)alloc((size_t)V_ * E_ * 2);       // 51.2 MB
  unsigned short* wxp  = (unsigned short*)alloc((size_t)E_ * G_ * 2);       // 4.2 MB
  unsigned short* whp3 = (unsigned short*)alloc((size_t)U_ * G_ * 2);       // 8.4 MB
  unsigned short* xpc  = (unsigned short*)alloc((size_t)TC_ * B_ * G_ * 2); // 67 MB
  unsigned short* hbuf = (unsigned short*)alloc((size_t)2 * B_ * U_ * 2);   // 1 MB
  float*          cst  = (float*)alloc((size_t)B_ * U_ * 4);                // 1 MB
  int*            cnt  = (int*)alloc((size_t)(T_ + 1) * NG_ * CPAD_ * 4);   // 263 KB

  // prep
  hipLaunchKernelGGL(cvt_bf16_kernel, dim3(12500), dim3(256), 0, stream, emb, embb, (long)V_ * E_);
  hipLaunchKernelGGL(pack_wx_kernel, dim3((E_ / 8) * G_ / 256), dim3(256), 0, stream, Wx, wxp, (E_ / 8) * G_);
  hipLaunchKernelGGL(pack_wh3_kernel, dim3(2048), dim3(256), 0, stream, Wh, whp3);
  hipMemsetAsync(hbuf, 0, (size_t)B_ * U_ * 2, stream);            // h(0) = 0 (buffer 0)
  hipMemsetAsync(cst, 0, (size_t)B_ * U_ * 4, stream);             // c(0) = 0
  hipMemsetAsync(cnt, 0, (size_t)(T_ + 1) * NG_ * CPAD_ * 4, stream);

  for (int ch = 0; ch < NCH_; ch++) {
    hipLaunchKernelGGL(xproj_kernel, dim3(TC_ * B_ / XP_BM, G_ / XP_BN), dim3(256), 0, stream,
                       sent, embb, wxp, bias, xpc, ch * TC_);
    hipLaunchKernelGGL(scan_kernel, dim3(NG_ * NS_), dim3(512), 0, stream,
                       xpc, whp3, hbuf, cst, cnt, ch * TC_);
  }
  hipLaunchKernelGGL(dense_kernel, dim3(B_), dim3(256), 0, stream,
                     hbuf /* h(256) lands in buffer 0 */, W1, b1, W2, b2, out);
}